// Round 9
// baseline (3237.482 us; speedup 1.0000x reference)
//
#include <hip/hip_runtime.h>
#include <hip/hip_bf16.h>

#define EPSV 1e-5f
constexpr int NB = 32;

typedef short bf16x8 __attribute__((ext_vector_type(8)));
typedef short short4v __attribute__((ext_vector_type(4)));
typedef float f32x4 __attribute__((ext_vector_type(4)));

__device__ inline float bf2f(short s) {
  return __uint_as_float(((unsigned)(unsigned short)s) << 16);
}
__device__ inline short f2bf(float f) {
  unsigned u = __float_as_uint(f);
  unsigned r = (u + 0x7FFFu + ((u >> 16) & 1u)) >> 16;
  return (short)r;
}
__device__ __forceinline__ void gld16(const void* g, void* l) {
  __builtin_amdgcn_global_load_lds(
      (const __attribute__((address_space(1))) void*)g,
      (__attribute__((address_space(3))) void*)l, 16, 0, 0);
}

// ---------------- zero fill (short8 stores) ----------------
__global__ __launch_bounds__(256) void zero_k(short* __restrict__ p, int n8) {
  bf16x8 z = {0,0,0,0,0,0,0,0};
  for (int i = blockIdx.x * 256 + threadIdx.x; i < n8; i += gridDim.x * 256)
    ((bf16x8*)p)[i] = z;
}

// ---------------- x stats (NCDHW, C=1) ----------------
__global__ __launch_bounds__(256) void reduce_partial_f32(
    const float* __restrict__ in, int spatial, float* __restrict__ part,
    int totb, int boff)
{
  const int b = blockIdx.x;
  const int nblk = gridDim.x;
  float s = 0.f, s2 = 0.f;
  for (int n = 0; n < NB; ++n) {
    const float* p = in + (size_t)n * spatial;
    for (int i = b * 256 + threadIdx.x; i < spatial; i += nblk * 256) {
      float v = p[i];
      s += v; s2 += v * v;
    }
  }
  __shared__ float sh[256], sh2[256];
  int tid = threadIdx.x;
  sh[tid] = s; sh2[tid] = s2;
  __syncthreads();
  for (int off = 128; off > 0; off >>= 1) {
    if (tid < off) { sh[tid] += sh[tid + off]; sh2[tid] += sh2[tid + off]; }
    __syncthreads();
  }
  if (tid == 0) {
    part[(size_t)(boff + b) * 2 + 0] = sh[0];
    part[(size_t)(boff + b) * 2 + 1] = sh2[0];
  }
}

__global__ __launch_bounds__(64) void reduce_final(
    const float* __restrict__ part, int nblk, int C, float* __restrict__ sums)
{
  const int c = blockIdx.x;
  float s = 0.f, s2 = 0.f;
  for (int b = threadIdx.x; b < nblk; b += 64) {
    s  += part[((size_t)c * nblk + b) * 2 + 0];
    s2 += part[((size_t)c * nblk + b) * 2 + 1];
  }
  for (int off = 32; off > 0; off >>= 1) {
    s  += __shfl_down(s, off);
    s2 += __shfl_down(s2, off);
  }
  if (threadIdx.x == 0) { sums[c] = s; sums[C + c] = s2; }
}

// ---------------- stats over padded CL64 interior ----------------
__global__ __launch_bounds__(256) void reduce_cl_pad(
    const short* __restrict__ y, int S, int INP, int totrows,
    float* __restrict__ part, int totb, int boff)
{
  const int S2 = S * S, S3 = S2 * S;
  const int b = blockIdx.x, nblk = gridDim.x;
  const int c8 = threadIdx.x & 7, seg = threadIdx.x >> 3;
  float s[8], s2[8];
  #pragma unroll
  for (int e = 0; e < 8; ++e) { s[e] = 0.f; s2[e] = 0.f; }
  for (int r = b * 32 + seg; r < totrows; r += nblk * 32) {
    int img = r / S3; int rr = r - img * S3;
    int d = rr / S2; int r2 = rr - d * S2;
    int h = r2 / S;  int w = r2 - h * S;
    const short* p = y + ((((size_t)img * INP + d + 3) * INP + h + 3) * INP + w + 3) * 64 + c8 * 8;
    bf16x8 v = *(const bf16x8*)p;
    #pragma unroll
    for (int e = 0; e < 8; ++e) {
      float f = bf2f(v[e]);
      s[e] += f; s2[e] += f * f;
    }
  }
  __shared__ float sh[32][64], sh2[32][64];
  #pragma unroll
  for (int e = 0; e < 8; ++e) { sh[seg][c8 * 8 + e] = s[e]; sh2[seg][c8 * 8 + e] = s2[e]; }
  __syncthreads();
  if (threadIdx.x < 64) {
    int c = threadIdx.x;
    float a = 0.f, a2 = 0.f;
    #pragma unroll
    for (int g = 0; g < 32; ++g) { a += sh[g][c]; a2 += sh2[g][c]; }
    part[((size_t)c * totb + boff + b) * 2 + 0] = a;
    part[((size_t)c * totb + boff + b) * 2 + 1] = a2;
  }
}

// ---------------- stats -> per-channel affine ----------------
__global__ __launch_bounds__(64) void aff_k(
    const float* __restrict__ st, const float* __restrict__ bias,
    float cnt_inv, int creal, float* __restrict__ a, float* __restrict__ c)
{
  int t = threadIdx.x;
  float mean = st[t] * cnt_inv;
  float var  = st[64 + t] * cnt_inv - mean * mean;
  float inv  = rsqrtf(var + EPSV);
  bool ok = t < creal;
  a[t] = ok ? inv : 0.f;
  c[t] = ok ? (-mean * inv + bias[t]) : 0.f;
}

// ---------------- in-place activation relu(a*y+c) over interior ----------
__global__ __launch_bounds__(256) void act_pad(
    short* __restrict__ y, int S, int INP, int totrows,
    const float* __restrict__ affa, const float* __restrict__ affc)
{
  const int S2 = S * S, S3 = S2 * S;
  const int total = totrows * 8;
  int idx0 = blockIdx.x * 256 + threadIdx.x;
  const int c8 = idx0 & 7;
  float af[8], cf[8];
  #pragma unroll
  for (int e = 0; e < 8; ++e) { af[e] = affa[c8 * 8 + e]; cf[e] = affc[c8 * 8 + e]; }
  for (int idx = idx0; idx < total; idx += gridDim.x * 256) {
    int r = idx >> 3;
    int img = r / S3; int rr = r - img * S3;
    int d = rr / S2; int r2 = rr - d * S2;
    int h = r2 / S;  int w = r2 - h * S;
    short* p = y + ((((size_t)img * INP + d + 3) * INP + h + 3) * INP + w + 3) * 64 + c8 * 8;
    bf16x8 v = *(const bf16x8*)p;
    bf16x8 o;
    #pragma unroll
    for (int e = 0; e < 8; ++e)
      o[e] = f2bf(fmaxf(af[e] * bf2f(v[e]) + cf[e], 0.f));
    *(bf16x8*)p = o;
  }
}

// ---------------- x -> normalized padded bf16 (70^3 per img) ----------------
__global__ __launch_bounds__(256) void norm_x(
    const float* __restrict__ x, const float* __restrict__ st,
    short* __restrict__ xpad)
{
  const float mean = st[0] / ((float)NB * 262144.0f);
  const float inv  = rsqrtf(st[1] / ((float)NB * 262144.0f) - mean * mean + EPSV);
  const int total = 32 * 64 * 64 * 8;
  for (int idx = blockIdx.x * 256 + threadIdx.x; idx < total; idx += gridDim.x * 256) {
    int w8 = idx & 7, h = (idx >> 3) & 63, d = (idx >> 9) & 63, img = idx >> 15;
    const float* xs = x + (((size_t)img << 18) + (d << 12) + (h << 6) + w8 * 8);
    short* o = xpad + (size_t)img * 343000 + ((d + 3) * 70 + h + 3) * 70 + (w8 * 8 + 3);
    #pragma unroll
    for (int e = 0; e < 8; ++e)
      o[e] = f2bf((xs[e] - mean) * inv);
  }
}

// ---------------- weight repacks ----------------
__global__ __launch_bounds__(256) void repack_k(
    const float* __restrict__ w, short* __restrict__ wt,
    int CO, int CIN, int COP)
{
  long total = 125L * COP * 64;
  for (long idx = (long)blockIdx.x * 256 + threadIdx.x; idx < total;
       idx += (long)gridDim.x * 256) {
    int tap = (int)(idx / (COP * 64));
    int r   = (int)(idx % (COP * 64));
    int co = r >> 6, ci = r & 63;
    float v = (co < CO && ci < CIN) ? w[((size_t)co * CIN + ci) * 125 + tap] : 0.f;
    wt[idx] = f2bf(v);
  }
}

// w0[52][125] -> w0t2[64 co][224 k'] with k' = (kd*5+kh)*8 + kw
__global__ __launch_bounds__(256) void repack_w0t2(
    const float* __restrict__ w, short* __restrict__ wt)
{
  for (int idx = blockIdx.x * 256 + threadIdx.x; idx < 64 * 224;
       idx += gridDim.x * 256) {
    int co = idx / 224, k = idx - co * 224;
    int kdh = k >> 3, kw = k & 7;
    float v = (co < 52 && kdh < 25 && kw < 5) ? w[co * 125 + kdh * 5 + kw] : 0.f;
    wt[idx] = f2bf(v);
  }
}

// ---------------- conv0: tap-major K=224 MFMA, xpad input ----------------
__global__ __launch_bounds__(256) void conv0_tap(
    const short* __restrict__ xpad, const short* __restrict__ w0t2,
    short* __restrict__ y0p, int n_in0)
{
  __shared__ __align__(16) char slab[1792 * 16];
  const int tid = threadIdx.x, wv = tid >> 6, ln = tid & 63;
  const int nl = ln & 15, cs = ln >> 4;
  const int ntile0 = blockIdx.x * 64, od = blockIdx.y, img = blockIdx.z;
  const short* xi = xpad + (size_t)(n_in0 + img) * 343000;

  #pragma unroll
  for (int p = 0; p < 7; ++p) {
    int qb = p * 256 + wv * 64;
    int q = qb + ln; if (q > 1599) q = 1599;
    int kdh = q >> 6, n = q & 63;
    int kd = kdh / 5, kh = kdh - kd * 5;
    int ng = ntile0 + n; if (ng > 1088) ng = 1088;
    int oh = ng / 33, ow = ng - oh * 33;
    const short* src = xi + (2 * od + kd) * 4900 + (2 * oh + kh) * 70 + 2 * ow;
    gld16(src, slab + qb * 16);
  }
  __syncthreads();

  f32x4 acc[4];
  #pragma unroll
  for (int mt = 0; mt < 4; ++mt) acc[mt] = (f32x4){0.f, 0.f, 0.f, 0.f};
  const int nn = wv * 16 + nl;
  #pragma unroll
  for (int c = 0; c < 7; ++c) {
    bf16x8 b = *(const bf16x8*)(slab + ((c * 4 + cs) * 64 + nn) * 16);
    #pragma unroll
    for (int mt = 0; mt < 4; ++mt) {
      bf16x8 a = *(const bf16x8*)(w0t2 + (mt * 16 + nl) * 224 + c * 32 + cs * 8);
      acc[mt] = __builtin_amdgcn_mfma_f32_16x16x32_bf16(a, b, acc[mt], 0, 0, 0);
    }
  }
  const int ng = ntile0 + nn;
  if (ng < 1089) {
    int oh = ng / 33, ow = ng - oh * 33;
    size_t base = ((((size_t)img * 39 + od + 3) * 39 + oh + 3) * 39 + ow + 3) * 64;
    #pragma unroll
    for (int mt = 0; mt < 4; ++mt) {
      short4v pk;
      #pragma unroll
      for (int r = 0; r < 4; ++r) pk[r] = f2bf(acc[mt][r]);
      *(short4v*)(y0p + base + mt * 16 + cs * 4) = pk;
    }
  }
}

// ---------------- slab swizzle (16B slots, XOR within 128B rows) ----------
__device__ inline int swz(int lin, int cs) {
  int row = lin >> 1;
  int slot = (((lin & 1) << 2) | cs) ^ (row & 7);
  return row * 128 + slot * 16;
}

// ---------------- main conv: pre-activated padded CL64 in/out -------------
// waves split N (NTW n-tiles of 16 each), all 4 m-tiles per wave.
template<int IN, int OUT, int OHG, int NTW>
__global__ __launch_bounds__(256, 3) void conv_ns2(
    const short* __restrict__ yin, const short* __restrict__ wt,
    short* __restrict__ yout, int n_out0)
{
  constexpr int INP = IN + 6;
  constexpr int OP  = OUT + 6;
  constexpr int W = 2 * OUT + 3;
  constexpr int H = 2 * OHG + 3;
  constexpr int LIN = H * W;
  constexpr int CHUNKS = LIN * 4;
  constexpr int PASSES = (CHUNKS + 255) / 256;
  constexpr int LINM = LIN - 1 - 4 * W - 4;

  __shared__ __align__(16) char slab[PASSES * 256 * 16];

  const int tid = threadIdx.x, wv = tid >> 6, ln = tid & 63;
  const int nl = ln & 15, cs = ln >> 4;
  const int oh0 = blockIdx.x * OHG;
  const int od  = blockIdx.y;
  const int img = blockIdx.z;

  int lb[NTW]; bool vld[NTW]; size_t obase[NTW];
  #pragma unroll
  for (int j = 0; j < NTW; ++j) {
    int nn = (wv * NTW + j) * 16 + nl;
    int ohl = nn / OUT, ow = nn - ohl * OUT;
    vld[j] = nn < OHG * OUT;
    int l = 2 * ohl * W + 2 * ow;
    lb[j] = (l > LINM) ? LINM : l;
    obase[j] = ((((size_t)(n_out0 + img) * OP + od + 3) * OP + oh0 + ohl + 3) * OP + ow + 3) * 64;
  }

  f32x4 acc[4][NTW];
  #pragma unroll
  for (int mt = 0; mt < 4; ++mt)
    #pragma unroll
    for (int j = 0; j < NTW; ++j) acc[mt][j] = (f32x4){0.f, 0.f, 0.f, 0.f};

  const short* yb = yin + (size_t)img * INP * INP * INP * 64;

  for (int ch = 0; ch < 2; ++ch) {
    for (int kd = 0; kd < 5; ++kd) {
      const int idp = 2 * od + kd;
      __syncthreads();
      // stage via global_load_lds, inverse-swizzled source
      #pragma unroll
      for (int p = 0; p < PASSES; ++p) {
        int qb = p * 256 + wv * 64;
        int q = qb + ln;
        int row = q >> 3;
        int sl = (q & 7) ^ (row & 7);
        int lin = row * 2 + (sl >> 2);
        if (lin > LIN - 1) lin = LIN - 1;
        int cs2 = sl & 3;
        int hl = lin / W, wl = lin - hl * W;
        const short* src = yb + (((size_t)idp * INP + 2 * oh0 + hl) * INP + wl) * 64
                           + ch * 32 + cs2 * 8;
        gld16(src, slab + qb * 16);
      }
      __syncthreads();
      for (int kh = 0; kh < 5; ++kh) {
        const int tapb = (kd * 5 + kh) * 5;
        bf16x8 afr[4][5];
        #pragma unroll
        for (int mt = 0; mt < 4; ++mt)
          #pragma unroll
          for (int kw = 0; kw < 5; ++kw)
            afr[mt][kw] = *(const bf16x8*)(
                wt + ((size_t)(tapb + kw) * 64 + mt * 16 + nl) * 64 + ch * 32 + cs * 8);
        #pragma unroll
        for (int kw = 0; kw < 5; ++kw) {
          bf16x8 b[NTW];
          #pragma unroll
          for (int j = 0; j < NTW; ++j)
            b[j] = *(const bf16x8*)(slab + swz(lb[j] + kh * W + kw, cs));
          #pragma unroll
          for (int mt = 0; mt < 4; ++mt)
            #pragma unroll
            for (int j = 0; j < NTW; ++j)
              acc[mt][j] = __builtin_amdgcn_mfma_f32_16x16x32_bf16(
                  afr[mt][kw], b[j], acc[mt][j], 0, 0, 0);
        }
      }
    }
  }

  #pragma unroll
  for (int j = 0; j < NTW; ++j) {
    if (!vld[j]) continue;
    #pragma unroll
    for (int mt = 0; mt < 4; ++mt) {
      short4v pk;
      #pragma unroll
      for (int r = 0; r < 4; ++r) pk[r] = f2bf(acc[mt][j][r]);
      *(short4v*)(yout + obase[j] + mt * 16 + cs * 4) = pk;
    }
  }
}

// ---------------- conv3: CO=16, padded pre-activated input ----------------
__global__ __launch_bounds__(256) void conv3_p(
    const short* __restrict__ y2p, const short* __restrict__ w3t,
    short* __restrict__ y3)
{
  constexpr int W = 15, LIN = 225, LINM = LIN - 1 - 4 * W - 4;
  __shared__ __align__(16) char slab[113 * 128];
  const int tid = threadIdx.x, wv = tid >> 6, ln = tid & 63;
  const int nl = ln & 15, cs = ln >> 4;
  const int od = blockIdx.x, img = blockIdx.y;

  const int nn = wv * 16 + nl;
  const bool vld = nn < 36;
  int ohl = nn / 6, ow = nn - ohl * 6;
  int lb = 2 * ohl * W + 2 * ow;
  if (lb > LINM) lb = LINM;
  const size_t obase = ((((size_t)img * 6 + od) * 6 + ohl) * 6 + ow) * 16;

  f32x4 acc = (f32x4){0.f, 0.f, 0.f, 0.f};
  const short* yb = y2p + (size_t)img * 4096 * 64;

  for (int ch = 0; ch < 2; ++ch) {
    for (int kd = 0; kd < 5; ++kd) {
      const int idp = 2 * od + kd;
      __syncthreads();
      for (int u = tid; u < 900; u += 256) {
        int lin = u >> 2, cs2 = u & 3;
        int hl = lin / 15, wl = lin - hl * 15;
        bf16x8 ld = *(const bf16x8*)(yb + (((size_t)idp * 16 + hl) * 16 + wl) * 64
                                     + ch * 32 + cs2 * 8);
        *(bf16x8*)(slab + swz(lin, cs2)) = ld;
      }
      __syncthreads();
      for (int kh = 0; kh < 5; ++kh) {
        const int tapb = (kd * 5 + kh) * 5;
        bf16x8 afr[5];
        #pragma unroll
        for (int kw = 0; kw < 5; ++kw)
          afr[kw] = *(const bf16x8*)(w3t + ((size_t)(tapb + kw) * 16 + nl) * 64
                                     + ch * 32 + cs * 8);
        #pragma unroll
        for (int kw = 0; kw < 5; ++kw) {
          bf16x8 b = *(const bf16x8*)(slab + swz(lb + kh * W + kw, cs));
          acc = __builtin_amdgcn_mfma_f32_16x16x32_bf16(afr[kw], b, acc, 0, 0, 0);
        }
      }
    }
  }
  if (vld) {
    short4v pk;
    #pragma unroll
    for (int r = 0; r < 4; ++r) pk[r] = f2bf(acc[r]);
    *(short4v*)(y3 + obase + cs * 4) = pk;
  }
}

// ---------------- global avg pool + affine batch-dim BN (y3 CL-16) --------
__global__ __launch_bounds__(320) void pool_bn(
    const short* __restrict__ y3, const float* __restrict__ gamma,
    const float* __restrict__ beta, float* __restrict__ out)
{
  __shared__ float pool[320];
  const int t = threadIdx.x;
  const int n = t / 10, c = t % 10;
  const short* p = y3 + (size_t)n * 216 * 16 + c;
  float s = 0.f;
  for (int i = 0; i < 216; ++i) s += bf2f(p[i * 16]);
  const float pv = s * (1.0f / 216.0f);
  pool[t] = pv;
  __syncthreads();
  float m = 0.f, m2 = 0.f;
  for (int nn = 0; nn < 32; ++nn) {
    float v = pool[nn * 10 + c];
    m += v; m2 += v * v;
  }
  m *= (1.0f / 32.0f);
  m2 = m2 * (1.0f / 32.0f) - m * m;
  out[t] = (pv - m) * rsqrtf(m2 + EPSV) * gamma[c] + beta[c];
}

// ---------------- launcher ----------------
extern "C" void kernel_launch(void* const* d_in, const int* in_sizes, int n_in,
                              void* d_out, int out_size, void* d_ws, size_t ws_size,
                              hipStream_t stream)
{
  const float* x  = (const float*)d_in[0];
  const float* w0 = (const float*)d_in[1];
  const float* b0 = (const float*)d_in[2];
  const float* w1 = (const float*)d_in[3];
  const float* b1 = (const float*)d_in[4];
  const float* w2 = (const float*)d_in[5];
  const float* b2 = (const float*)d_in[6];
  const float* w3 = (const float*)d_in[7];
  const float* gamma = (const float*)d_in[8];
  const float* beta  = (const float*)d_in[9];
  float* out = (float*)d_out;

  char* base = (char*)d_ws;
  size_t off = 0;
  auto alloc = [&](size_t bytes) -> void* {
    void* p = base + off;
    off = (off + bytes + 255) & ~(size_t)255;
    return p;
  };
  short* xpad = (short*)alloc((size_t)10976064 * 2);        // 21.9 MB
  short* y1p  = (short*)alloc((size_t)28311552 * 2);        // 56.6 MB
  short* y2p  = (short*)alloc((size_t)8388608 * 2);         // 16.8 MB
  short* y3   = (short*)alloc((size_t)110592 * 2);
  short* w1t  = (short*)alloc((size_t)512000 * 2);
  short* w2t  = (short*)alloc((size_t)512000 * 2);
  short* w3t  = (short*)alloc((size_t)128000 * 2);
  short* w0t2 = (short*)alloc((size_t)14336 * 2);
  float* st_in = (float*)alloc(1024);
  float* st0 = (float*)alloc(1024);
  float* st1 = (float*)alloc(1024);
  float* st2 = (float*)alloc(1024);
  float* a0 = (float*)alloc(256); float* c0 = (float*)alloc(256);
  float* a1 = (float*)alloc(256); float* c1 = (float*)alloc(256);
  float* a2 = (float*)alloc(256); float* c2 = (float*)alloc(256);
  float* part = (float*)alloc(524288);
  short* y0p = (short*)(base + off);
  size_t rem = (ws_size > off + 256) ? (ws_size - off - 256) : 0;
  const size_t Y0_IMG = (size_t)59319 * 64;                 // 39^3 * 64
  int CH;
  if      (rem >= Y0_IMG * 32 * 2) CH = 32;
  else if (rem >= Y0_IMG * 16 * 2) CH = 16;
  else if (rem >= Y0_IMG * 8 * 2)  CH = 8;
  else if (rem >= Y0_IMG * 4 * 2)  CH = 4;
  else if (rem >= Y0_IMG * 2 * 2)  CH = 2;
  else                             CH = 1;
  const int nch = 32 / CH;

  // ---- zero padded buffers (pads must be 0; interiors overwritten) ----
  zero_k<<<2048, 256, 0, stream>>>(xpad, 10976064 / 8);
  zero_k<<<2048, 256, 0, stream>>>(y0p, (int)(Y0_IMG * CH / 8));
  zero_k<<<2048, 256, 0, stream>>>(y1p, 28311552 / 8);
  zero_k<<<1024, 256, 0, stream>>>(y2p, 8388608 / 8);

  // ---- weight repacks ----
  repack_k<<<512, 256, 0, stream>>>(w1, w1t, 52, 52, 64);
  repack_k<<<512, 256, 0, stream>>>(w2, w2t, 52, 52, 64);
  repack_k<<<256, 256, 0, stream>>>(w3, w3t, 10, 52, 16);
  repack_w0t2<<<56, 256, 0, stream>>>(w0, w0t2);

  // ---- x stats + normalized padded x ----
  reduce_partial_f32<<<128, 256, 0, stream>>>(x, 262144, part, 128, 0);
  reduce_final<<<1, 64, 0, stream>>>(part, 128, 1, st_in);
  norm_x<<<2048, 256, 0, stream>>>(x, st_in, xpad);

  const float cnt0 = 1.0f / ((float)NB * 35937.0f);
  const float cnt1 = 1.0f / ((float)NB * 5832.0f);
  const float cnt2 = 1.0f / ((float)NB * 1000.0f);

  if (CH == 32) {
    conv0_tap<<<dim3(18, 33, 32), 256, 0, stream>>>(xpad, w0t2, y0p, 0);
    reduce_cl_pad<<<512, 256, 0, stream>>>(y0p, 33, 39, 32 * 35937, part, 512, 0);
    reduce_final<<<64, 64, 0, stream>>>(part, 512, 64, st0);
    aff_k<<<1, 64, 0, stream>>>(st0, b0, cnt0, 52, a0, c0);
    act_pad<<<2048, 256, 0, stream>>>(y0p, 33, 39, 32 * 35937, a0, c0);
    conv_ns2<33, 18, 6, 2><<<dim3(3, 18, 32), 256, 0, stream>>>(y0p, w1t, y1p, 0);
  } else {
    for (int ck = 0; ck < nch; ++ck) {
      conv0_tap<<<dim3(18, 33, CH), 256, 0, stream>>>(xpad, w0t2, y0p, ck * CH);
      reduce_cl_pad<<<16, 256, 0, stream>>>(y0p, 33, 39, CH * 35937, part, nch * 16, ck * 16);
    }
    reduce_final<<<64, 64, 0, stream>>>(part, nch * 16, 64, st0);
    aff_k<<<1, 64, 0, stream>>>(st0, b0, cnt0, 52, a0, c0);
    for (int ck = 0; ck < nch; ++ck) {
      conv0_tap<<<dim3(18, 33, CH), 256, 0, stream>>>(xpad, w0t2, y0p, ck * CH);
      act_pad<<<2048, 256, 0, stream>>>(y0p, 33, 39, CH * 35937, a0, c0);
      conv_ns2<33, 18, 6, 2><<<dim3(3, 18, CH), 256, 0, stream>>>(y0p, w1t, y1p, ck * CH);
    }
  }

  reduce_cl_pad<<<128, 256, 0, stream>>>(y1p, 18, 24, 32 * 5832, part, 128, 0);
  reduce_final<<<64, 64, 0, stream>>>(part, 128, 64, st1);
  aff_k<<<1, 64, 0, stream>>>(st1, b1, cnt1, 52, a1, c1);
  act_pad<<<1024, 256, 0, stream>>>(y1p, 18, 24, 32 * 5832, a1, c1);

  conv_ns2<18, 10, 5, 1><<<dim3(2, 10, 32), 256, 0, stream>>>(y1p, w2t, y2p, 0);

  reduce_cl_pad<<<32, 256, 0, stream>>>(y2p, 10, 16, 32 * 1000, part, 32, 0);
  reduce_final<<<64, 64, 0, stream>>>(part, 32, 64, st2);
  aff_k<<<1, 64, 0, stream>>>(st2, b2, cnt2, 52, a2, c2);
  act_pad<<<256, 256, 0, stream>>>(y2p, 10, 16, 32 * 1000, a2, c2);

  conv3_p<<<dim3(6, 32), 256, 0, stream>>>(y2p, w3t, y3);

  pool_bn<<<1, 320, 0, stream>>>(y3, gamma, beta, out);
}

// Round 10
// 3013.652 us; speedup vs baseline: 1.0743x; 1.0743x over previous
//
#include <hip/hip_runtime.h>
#include <hip/hip_bf16.h>

#define EPSV 1e-5f
constexpr int NB = 32;

typedef short bf16x8 __attribute__((ext_vector_type(8)));
typedef short short4v __attribute__((ext_vector_type(4)));
typedef float f32x4 __attribute__((ext_vector_type(4)));

__device__ inline float bf2f(short s) {
  return __uint_as_float(((unsigned)(unsigned short)s) << 16);
}
__device__ inline short f2bf(float f) {
  unsigned u = __float_as_uint(f);
  unsigned r = (u + 0x7FFFu + ((u >> 16) & 1u)) >> 16;
  return (short)r;
}
__device__ __forceinline__ void gld16(const void* g, void* l) {
  __builtin_amdgcn_global_load_lds(
      (const __attribute__((address_space(1))) void*)g,
      (__attribute__((address_space(3))) void*)l, 16, 0, 0);
}

// A-fragment loader: 20 frags (4 m-tiles x 5 kw) for one (ch,kd,kh)
__device__ __forceinline__ void loada(bf16x8 (&dst)[4][5], const short* __restrict__ wt,
                                      int kd, int kh, int ch, int nl, int cs) {
  const int tapb = (kd * 5 + kh) * 5;
  #pragma unroll
  for (int mt = 0; mt < 4; ++mt)
    #pragma unroll
    for (int kw = 0; kw < 5; ++kw)
      dst[mt][kw] = *(const bf16x8*)(
          wt + ((size_t)(tapb + kw) * 64 + mt * 16 + nl) * 64 + ch * 32 + cs * 8);
}

// ---------------- zero fill ----------------
__global__ __launch_bounds__(256) void zero_k(short* __restrict__ p, int n8) {
  bf16x8 z = {0,0,0,0,0,0,0,0};
  for (int i = blockIdx.x * 256 + threadIdx.x; i < n8; i += gridDim.x * 256)
    ((bf16x8*)p)[i] = z;
}

// ---------------- x stats ----------------
__global__ __launch_bounds__(256) void reduce_partial_f32(
    const float* __restrict__ in, int spatial, float* __restrict__ part,
    int totb, int boff)
{
  const int b = blockIdx.x;
  const int nblk = gridDim.x;
  float s = 0.f, s2 = 0.f;
  for (int n = 0; n < NB; ++n) {
    const float* p = in + (size_t)n * spatial;
    for (int i = b * 256 + threadIdx.x; i < spatial; i += nblk * 256) {
      float v = p[i];
      s += v; s2 += v * v;
    }
  }
  __shared__ float sh[256], sh2[256];
  int tid = threadIdx.x;
  sh[tid] = s; sh2[tid] = s2;
  __syncthreads();
  for (int off = 128; off > 0; off >>= 1) {
    if (tid < off) { sh[tid] += sh[tid + off]; sh2[tid] += sh2[tid + off]; }
    __syncthreads();
  }
  if (tid == 0) {
    part[(size_t)(boff + b) * 2 + 0] = sh[0];
    part[(size_t)(boff + b) * 2 + 1] = sh2[0];
  }
}

__global__ __launch_bounds__(64) void reduce_final(
    const float* __restrict__ part, int nblk, int C, float* __restrict__ sums)
{
  const int c = blockIdx.x;
  float s = 0.f, s2 = 0.f;
  for (int b = threadIdx.x; b < nblk; b += 64) {
    s  += part[((size_t)c * nblk + b) * 2 + 0];
    s2 += part[((size_t)c * nblk + b) * 2 + 1];
  }
  for (int off = 32; off > 0; off >>= 1) {
    s  += __shfl_down(s, off);
    s2 += __shfl_down(s2, off);
  }
  if (threadIdx.x == 0) { sums[c] = s; sums[C + c] = s2; }
}

// ---------------- stats over padded CL64 interior ----------------
__global__ __launch_bounds__(256) void reduce_cl_pad(
    const short* __restrict__ y, int S, int INP, int totrows,
    float* __restrict__ part, int totb, int boff)
{
  const int S2 = S * S, S3 = S2 * S;
  const int b = blockIdx.x, nblk = gridDim.x;
  const int c8 = threadIdx.x & 7, seg = threadIdx.x >> 3;
  float s[8], s2[8];
  #pragma unroll
  for (int e = 0; e < 8; ++e) { s[e] = 0.f; s2[e] = 0.f; }
  for (int r = b * 32 + seg; r < totrows; r += nblk * 32) {
    int img = r / S3; int rr = r - img * S3;
    int d = rr / S2; int r2 = rr - d * S2;
    int h = r2 / S;  int w = r2 - h * S;
    const short* p = y + ((((size_t)img * INP + d + 3) * INP + h + 3) * INP + w + 3) * 64 + c8 * 8;
    bf16x8 v = *(const bf16x8*)p;
    #pragma unroll
    for (int e = 0; e < 8; ++e) {
      float f = bf2f(v[e]);
      s[e] += f; s2[e] += f * f;
    }
  }
  __shared__ float sh[32][64], sh2[32][64];
  #pragma unroll
  for (int e = 0; e < 8; ++e) { sh[seg][c8 * 8 + e] = s[e]; sh2[seg][c8 * 8 + e] = s2[e]; }
  __syncthreads();
  if (threadIdx.x < 64) {
    int c = threadIdx.x;
    float a = 0.f, a2 = 0.f;
    #pragma unroll
    for (int g = 0; g < 32; ++g) { a += sh[g][c]; a2 += sh2[g][c]; }
    part[((size_t)c * totb + boff + b) * 2 + 0] = a;
    part[((size_t)c * totb + boff + b) * 2 + 1] = a2;
  }
}

// ---------------- stats -> per-channel affine ----------------
__global__ __launch_bounds__(64) void aff_k(
    const float* __restrict__ st, const float* __restrict__ bias,
    float cnt_inv, int creal, float* __restrict__ a, float* __restrict__ c)
{
  int t = threadIdx.x;
  float mean = st[t] * cnt_inv;
  float var  = st[64 + t] * cnt_inv - mean * mean;
  float inv  = rsqrtf(var + EPSV);
  bool ok = t < creal;
  a[t] = ok ? inv : 0.f;
  c[t] = ok ? (-mean * inv + bias[t]) : 0.f;
}

// ---------------- in-place activation relu(a*y+c) over interior ----------
__global__ __launch_bounds__(256) void act_pad(
    short* __restrict__ y, int S, int INP, int totrows,
    const float* __restrict__ affa, const float* __restrict__ affc)
{
  const int S2 = S * S, S3 = S2 * S;
  const int total = totrows * 8;
  int idx0 = blockIdx.x * 256 + threadIdx.x;
  const int c8 = idx0 & 7;
  float af[8], cf[8];
  #pragma unroll
  for (int e = 0; e < 8; ++e) { af[e] = affa[c8 * 8 + e]; cf[e] = affc[c8 * 8 + e]; }
  for (int idx = idx0; idx < total; idx += gridDim.x * 256) {
    int r = idx >> 3;
    int img = r / S3; int rr = r - img * S3;
    int d = rr / S2; int r2 = rr - d * S2;
    int h = r2 / S;  int w = r2 - h * S;
    short* p = y + ((((size_t)img * INP + d + 3) * INP + h + 3) * INP + w + 3) * 64 + c8 * 8;
    bf16x8 v = *(const bf16x8*)p;
    bf16x8 o;
    #pragma unroll
    for (int e = 0; e < 8; ++e)
      o[e] = f2bf(fmaxf(af[e] * bf2f(v[e]) + cf[e], 0.f));
    *(bf16x8*)p = o;
  }
}

// ---------------- x -> normalized padded bf16 ----------------
__global__ __launch_bounds__(256) void norm_x(
    const float* __restrict__ x, const float* __restrict__ st,
    short* __restrict__ xpad)
{
  const float mean = st[0] / ((float)NB * 262144.0f);
  const float inv  = rsqrtf(st[1] / ((float)NB * 262144.0f) - mean * mean + EPSV);
  const int total = 32 * 64 * 64 * 8;
  for (int idx = blockIdx.x * 256 + threadIdx.x; idx < total; idx += gridDim.x * 256) {
    int w8 = idx & 7, h = (idx >> 3) & 63, d = (idx >> 9) & 63, img = idx >> 15;
    const float* xs = x + (((size_t)img << 18) + (d << 12) + (h << 6) + w8 * 8);
    short* o = xpad + (size_t)img * 343000 + ((d + 3) * 70 + h + 3) * 70 + (w8 * 8 + 3);
    #pragma unroll
    for (int e = 0; e < 8; ++e)
      o[e] = f2bf((xs[e] - mean) * inv);
  }
}

// ---------------- weight repacks ----------------
__global__ __launch_bounds__(256) void repack_k(
    const float* __restrict__ w, short* __restrict__ wt,
    int CO, int CIN, int COP)
{
  long total = 125L * COP * 64;
  for (long idx = (long)blockIdx.x * 256 + threadIdx.x; idx < total;
       idx += (long)gridDim.x * 256) {
    int tap = (int)(idx / (COP * 64));
    int r   = (int)(idx % (COP * 64));
    int co = r >> 6, ci = r & 63;
    float v = (co < CO && ci < CIN) ? w[((size_t)co * CIN + ci) * 125 + tap] : 0.f;
    wt[idx] = f2bf(v);
  }
}

__global__ __launch_bounds__(256) void repack_w0t2(
    const float* __restrict__ w, short* __restrict__ wt)
{
  for (int idx = blockIdx.x * 256 + threadIdx.x; idx < 64 * 224;
       idx += gridDim.x * 256) {
    int co = idx / 224, k = idx - co * 224;
    int kdh = k >> 3, kw = k & 7;
    float v = (co < 52 && kdh < 25 && kw < 5) ? w[co * 125 + kdh * 5 + kw] : 0.f;
    wt[idx] = f2bf(v);
  }
}

// ---------------- conv0: tap-major K=224 MFMA, A-frags hoisted -------------
__global__ __launch_bounds__(256) void conv0_tap(
    const short* __restrict__ xpad, const short* __restrict__ w0t2,
    short* __restrict__ y0p, int n_in0)
{
  __shared__ __align__(16) char slab[1792 * 16];
  const int tid = threadIdx.x, wv = tid >> 6, ln = tid & 63;
  const int nl = ln & 15, cs = ln >> 4;
  const int ntile0 = blockIdx.x * 64, od = blockIdx.y, img = blockIdx.z;
  const short* xi = xpad + (size_t)(n_in0 + img) * 343000;

  // hoist all 28 A-frags; loads issued before staging so latency overlaps
  bf16x8 afr[7][4];
  #pragma unroll
  for (int c = 0; c < 7; ++c)
    #pragma unroll
    for (int mt = 0; mt < 4; ++mt)
      afr[c][mt] = *(const bf16x8*)(w0t2 + (mt * 16 + nl) * 224 + c * 32 + cs * 8);

  #pragma unroll
  for (int p = 0; p < 7; ++p) {
    int qb = p * 256 + wv * 64;
    int q = qb + ln; if (q > 1599) q = 1599;
    int kdh = q >> 6, n = q & 63;
    int kd = kdh / 5, kh = kdh - kd * 5;
    int ng = ntile0 + n; if (ng > 1088) ng = 1088;
    int oh = ng / 33, ow = ng - oh * 33;
    const short* src = xi + (2 * od + kd) * 4900 + (2 * oh + kh) * 70 + 2 * ow;
    gld16(src, slab + qb * 16);
  }
  __syncthreads();

  f32x4 acc[4];
  #pragma unroll
  for (int mt = 0; mt < 4; ++mt) acc[mt] = (f32x4){0.f, 0.f, 0.f, 0.f};
  const int nn = wv * 16 + nl;
  #pragma unroll
  for (int c = 0; c < 7; ++c) {
    bf16x8 b = *(const bf16x8*)(slab + ((c * 4 + cs) * 64 + nn) * 16);
    #pragma unroll
    for (int mt = 0; mt < 4; ++mt)
      acc[mt] = __builtin_amdgcn_mfma_f32_16x16x32_bf16(afr[c][mt], b, acc[mt], 0, 0, 0);
  }
  const int ng = ntile0 + nn;
  if (ng < 1089) {
    int oh = ng / 33, ow = ng - oh * 33;
    size_t base = ((((size_t)img * 39 + od + 3) * 39 + oh + 3) * 39 + ow + 3) * 64;
    #pragma unroll
    for (int mt = 0; mt < 4; ++mt) {
      short4v pk;
      #pragma unroll
      for (int r = 0; r < 4; ++r) pk[r] = f2bf(acc[mt][r]);
      *(short4v*)(y0p + base + mt * 16 + cs * 4) = pk;
    }
  }
}

// ---------------- slab swizzle ----------------
__device__ inline int swz(int lin, int cs) {
  int row = lin >> 1;
  int slot = (((lin & 1) << 2) | cs) ^ (row & 7);
  return row * 128 + slot * 16;
}

// ---------------- main conv, double-buffered A-prefetch across kh ---------
template<int IN, int OUT, int OHG, int NTW>
__global__ __launch_bounds__(256, 2) void conv_ns2(
    const short* __restrict__ yin, const short* __restrict__ wt,
    short* __restrict__ yout, int n_out0)
{
  constexpr int INP = IN + 6;
  constexpr int OP  = OUT + 6;
  constexpr int W = 2 * OUT + 3;
  constexpr int H = 2 * OHG + 3;
  constexpr int LIN = H * W;
  constexpr int CHUNKS = LIN * 4;
  constexpr int PASSES = (CHUNKS + 255) / 256;
  constexpr int LINM = LIN - 1 - 4 * W - 4;

  __shared__ __align__(16) char slab[PASSES * 256 * 16];

  const int tid = threadIdx.x, wv = tid >> 6, ln = tid & 63;
  const int nl = ln & 15, cs = ln >> 4;
  const int oh0 = blockIdx.x * OHG;
  const int od  = blockIdx.y;
  const int img = blockIdx.z;

  int lb[NTW]; bool vld[NTW]; size_t obase[NTW];
  #pragma unroll
  for (int j = 0; j < NTW; ++j) {
    int nn = (wv * NTW + j) * 16 + nl;
    int ohl = nn / OUT, ow = nn - ohl * OUT;
    vld[j] = nn < OHG * OUT;
    int l = 2 * ohl * W + 2 * ow;
    lb[j] = (l > LINM) ? LINM : l;
    obase[j] = ((((size_t)(n_out0 + img) * OP + od + 3) * OP + oh0 + ohl + 3) * OP + ow + 3) * 64;
  }

  f32x4 acc[4][NTW];
  #pragma unroll
  for (int mt = 0; mt < 4; ++mt)
    #pragma unroll
    for (int j = 0; j < NTW; ++j) acc[mt][j] = (f32x4){0.f, 0.f, 0.f, 0.f};

  const short* yb = yin + (size_t)img * INP * INP * INP * 64;

  for (int ch = 0; ch < 2; ++ch) {
    for (int kd = 0; kd < 5; ++kd) {
      const int idp = 2 * od + kd;
      __syncthreads();
      // stage B slab via global_load_lds (inverse-swizzled source)
      #pragma unroll
      for (int p = 0; p < PASSES; ++p) {
        int qb = p * 256 + wv * 64;
        int q = qb + ln;
        int row = q >> 3;
        int sl = (q & 7) ^ (row & 7);
        int lin = row * 2 + (sl >> 2);
        if (lin > LIN - 1) lin = LIN - 1;
        int cs2 = sl & 3;
        int hl = lin / W, wl = lin - hl * W;
        const short* src = yb + (((size_t)idp * INP + 2 * oh0 + hl) * INP + wl) * 64
                           + ch * 32 + cs2 * 8;
        gld16(src, slab + qb * 16);
      }
      // prefetch kh=0 A-frags; latency overlaps the stage drain below
      bf16x8 afr[2][4][5];
      loada(afr[0], wt, kd, 0, ch, nl, cs);
      __syncthreads();
      #pragma unroll
      for (int kh = 0; kh < 5; ++kh) {
        if (kh < 4)
          loada(afr[(kh + 1) & 1], wt, kd, kh + 1, ch, nl, cs);
        #pragma unroll
        for (int kw = 0; kw < 5; ++kw) {
          bf16x8 b[NTW];
          #pragma unroll
          for (int j = 0; j < NTW; ++j)
            b[j] = *(const bf16x8*)(slab + swz(lb[j] + kh * W + kw, cs));
          #pragma unroll
          for (int mt = 0; mt < 4; ++mt)
            #pragma unroll
            for (int j = 0; j < NTW; ++j)
              acc[mt][j] = __builtin_amdgcn_mfma_f32_16x16x32_bf16(
                  afr[kh & 1][mt][kw], b[j], acc[mt][j], 0, 0, 0);
        }
      }
    }
  }

  #pragma unroll
  for (int j = 0; j < NTW; ++j) {
    if (!vld[j]) continue;
    #pragma unroll
    for (int mt = 0; mt < 4; ++mt) {
      short4v pk;
      #pragma unroll
      for (int r = 0; r < 4; ++r) pk[r] = f2bf(acc[mt][j][r]);
      *(short4v*)(yout + obase[j] + mt * 16 + cs * 4) = pk;
    }
  }
}

// ---------------- conv3: CO=16 ----------------
__global__ __launch_bounds__(256) void conv3_p(
    const short* __restrict__ y2p, const short* __restrict__ w3t,
    short* __restrict__ y3)
{
  constexpr int W = 15, LIN = 225, LINM = LIN - 1 - 4 * W - 4;
  __shared__ __align__(16) char slab[113 * 128];
  const int tid = threadIdx.x, wv = tid >> 6, ln = tid & 63;
  const int nl = ln & 15, cs = ln >> 4;
  const int od = blockIdx.x, img = blockIdx.y;

  const int nn = wv * 16 + nl;
  const bool vld = nn < 36;
  int ohl = nn / 6, ow = nn - ohl * 6;
  int lb = 2 * ohl * W + 2 * ow;
  if (lb > LINM) lb = LINM;
  const size_t obase = ((((size_t)img * 6 + od) * 6 + ohl) * 6 + ow) * 16;

  f32x4 acc = (f32x4){0.f, 0.f, 0.f, 0.f};
  const short* yb = y2p + (size_t)img * 4096 * 64;

  for (int ch = 0; ch < 2; ++ch) {
    for (int kd = 0; kd < 5; ++kd) {
      const int idp = 2 * od + kd;
      __syncthreads();
      for (int u = tid; u < 900; u += 256) {
        int lin = u >> 2, cs2 = u & 3;
        int hl = lin / 15, wl = lin - hl * 15;
        bf16x8 ld = *(const bf16x8*)(yb + (((size_t)idp * 16 + hl) * 16 + wl) * 64
                                     + ch * 32 + cs2 * 8);
        *(bf16x8*)(slab + swz(lin, cs2)) = ld;
      }
      __syncthreads();
      for (int kh = 0; kh < 5; ++kh) {
        const int tapb = (kd * 5 + kh) * 5;
        bf16x8 afr[5];
        #pragma unroll
        for (int kw = 0; kw < 5; ++kw)
          afr[kw] = *(const bf16x8*)(w3t + ((size_t)(tapb + kw) * 16 + nl) * 64
                                     + ch * 32 + cs * 8);
        #pragma unroll
        for (int kw = 0; kw < 5; ++kw) {
          bf16x8 b = *(const bf16x8*)(slab + swz(lb + kh * W + kw, cs));
          acc = __builtin_amdgcn_mfma_f32_16x16x32_bf16(afr[kw], b, acc, 0, 0, 0);
        }
      }
    }
  }
  if (vld) {
    short4v pk;
    #pragma unroll
    for (int r = 0; r < 4; ++r) pk[r] = f2bf(acc[r]);
    *(short4v*)(y3 + obase + cs * 4) = pk;
  }
}

// ---------------- pool + batch BN ----------------
__global__ __launch_bounds__(320) void pool_bn(
    const short* __restrict__ y3, const float* __restrict__ gamma,
    const float* __restrict__ beta, float* __restrict__ out)
{
  __shared__ float pool[320];
  const int t = threadIdx.x;
  const int n = t / 10, c = t % 10;
  const short* p = y3 + (size_t)n * 216 * 16 + c;
  float s = 0.f;
  for (int i = 0; i < 216; ++i) s += bf2f(p[i * 16]);
  const float pv = s * (1.0f / 216.0f);
  pool[t] = pv;
  __syncthreads();
  float m = 0.f, m2 = 0.f;
  for (int nn = 0; nn < 32; ++nn) {
    float v = pool[nn * 10 + c];
    m += v; m2 += v * v;
  }
  m *= (1.0f / 32.0f);
  m2 = m2 * (1.0f / 32.0f) - m * m;
  out[t] = (pv - m) * rsqrtf(m2 + EPSV) * gamma[c] + beta[c];
}

// ---------------- launcher ----------------
extern "C" void kernel_launch(void* const* d_in, const int* in_sizes, int n_in,
                              void* d_out, int out_size, void* d_ws, size_t ws_size,
                              hipStream_t stream)
{
  const float* x  = (const float*)d_in[0];
  const float* w0 = (const float*)d_in[1];
  const float* b0 = (const float*)d_in[2];
  const float* w1 = (const float*)d_in[3];
  const float* b1 = (const float*)d_in[4];
  const float* w2 = (const float*)d_in[5];
  const float* b2 = (const float*)d_in[6];
  const float* w3 = (const float*)d_in[7];
  const float* gamma = (const float*)d_in[8];
  const float* beta  = (const float*)d_in[9];
  float* out = (float*)d_out;

  char* base = (char*)d_ws;
  size_t off = 0;
  auto alloc = [&](size_t bytes) -> void* {
    void* p = base + off;
    off = (off + bytes + 255) & ~(size_t)255;
    return p;
  };
  short* xpad = (short*)alloc((size_t)10976064 * 2);        // 21.9 MB
  short* y1p  = (short*)alloc((size_t)28311552 * 2);        // 56.6 MB
  short* y2p  = (short*)alloc((size_t)8388608 * 2);         // 16.8 MB
  short* y3   = (short*)alloc((size_t)110592 * 2);
  short* w1t  = (short*)alloc((size_t)512000 * 2);
  short* w2t  = (short*)alloc((size_t)512000 * 2);
  short* w3t  = (short*)alloc((size_t)128000 * 2);
  short* w0t2 = (short*)alloc((size_t)14336 * 2);
  float* st_in = (float*)alloc(1024);
  float* st0 = (float*)alloc(1024);
  float* st1 = (float*)alloc(1024);
  float* st2 = (float*)alloc(1024);
  float* a0 = (float*)alloc(256); float* c0 = (float*)alloc(256);
  float* a1 = (float*)alloc(256); float* c1 = (float*)alloc(256);
  float* a2 = (float*)alloc(256); float* c2 = (float*)alloc(256);
  float* part = (float*)alloc(524288);
  short* y0p = (short*)(base + off);
  size_t rem = (ws_size > off + 256) ? (ws_size - off - 256) : 0;
  const size_t Y0_IMG = (size_t)59319 * 64;                 // 39^3 * 64
  int CH;
  if      (rem >= Y0_IMG * 32 * 2) CH = 32;
  else if (rem >= Y0_IMG * 16 * 2) CH = 16;
  else if (rem >= Y0_IMG * 8 * 2)  CH = 8;
  else if (rem >= Y0_IMG * 4 * 2)  CH = 4;
  else if (rem >= Y0_IMG * 2 * 2)  CH = 2;
  else                             CH = 1;
  const int nch = 32 / CH;

  zero_k<<<2048, 256, 0, stream>>>(xpad, 10976064 / 8);
  zero_k<<<2048, 256, 0, stream>>>(y0p, (int)(Y0_IMG * CH / 8));
  zero_k<<<2048, 256, 0, stream>>>(y1p, 28311552 / 8);
  zero_k<<<1024, 256, 0, stream>>>(y2p, 8388608 / 8);

  repack_k<<<512, 256, 0, stream>>>(w1, w1t, 52, 52, 64);
  repack_k<<<512, 256, 0, stream>>>(w2, w2t, 52, 52, 64);
  repack_k<<<256, 256, 0, stream>>>(w3, w3t, 10, 52, 16);
  repack_w0t2<<<56, 256, 0, stream>>>(w0, w0t2);

  reduce_partial_f32<<<128, 256, 0, stream>>>(x, 262144, part, 128, 0);
  reduce_final<<<1, 64, 0, stream>>>(part, 128, 1, st_in);
  norm_x<<<2048, 256, 0, stream>>>(x, st_in, xpad);

  const float cnt0 = 1.0f / ((float)NB * 35937.0f);
  const float cnt1 = 1.0f / ((float)NB * 5832.0f);
  const float cnt2 = 1.0f / ((float)NB * 1000.0f);

  if (CH == 32) {
    conv0_tap<<<dim3(18, 33, 32), 256, 0, stream>>>(xpad, w0t2, y0p, 0);
    reduce_cl_pad<<<512, 256, 0, stream>>>(y0p, 33, 39, 32 * 35937, part, 512, 0);
    reduce_final<<<64, 64, 0, stream>>>(part, 512, 64, st0);
    aff_k<<<1, 64, 0, stream>>>(st0, b0, cnt0, 52, a0, c0);
    act_pad<<<2048, 256, 0, stream>>>(y0p, 33, 39, 32 * 35937, a0, c0);
    conv_ns2<33, 18, 6, 2><<<dim3(3, 18, 32), 256, 0, stream>>>(y0p, w1t, y1p, 0);
  } else {
    for (int ck = 0; ck < nch; ++ck) {
      conv0_tap<<<dim3(18, 33, CH), 256, 0, stream>>>(xpad, w0t2, y0p, ck * CH);
      reduce_cl_pad<<<16, 256, 0, stream>>>(y0p, 33, 39, CH * 35937, part, nch * 16, ck * 16);
    }
    reduce_final<<<64, 64, 0, stream>>>(part, nch * 16, 64, st0);
    aff_k<<<1, 64, 0, stream>>>(st0, b0, cnt0, 52, a0, c0);
    for (int ck = 0; ck < nch; ++ck) {
      conv0_tap<<<dim3(18, 33, CH), 256, 0, stream>>>(xpad, w0t2, y0p, ck * CH);
      act_pad<<<2048, 256, 0, stream>>>(y0p, 33, 39, CH * 35937, a0, c0);
      conv_ns2<33, 18, 6, 2><<<dim3(3, 18, CH), 256, 0, stream>>>(y0p, w1t, y1p, ck * CH);
    }
  }

  reduce_cl_pad<<<128, 256, 0, stream>>>(y1p, 18, 24, 32 * 5832, part, 128, 0);
  reduce_final<<<64, 64, 0, stream>>>(part, 128, 64, st1);
  aff_k<<<1, 64, 0, stream>>>(st1, b1, cnt1, 52, a1, c1);
  act_pad<<<1024, 256, 0, stream>>>(y1p, 18, 24, 32 * 5832, a1, c1);

  conv_ns2<18, 10, 10, 2><<<dim3(1, 10, 32), 256, 0, stream>>>(y1p, w2t, y2p, 0);

  reduce_cl_pad<<<32, 256, 0, stream>>>(y2p, 10, 16, 32 * 1000, part, 32, 0);
  reduce_final<<<64, 64, 0, stream>>>(part, 32, 64, st2);
  aff_k<<<1, 64, 0, stream>>>(st2, b2, cnt2, 52, a2, c2);
  act_pad<<<256, 256, 0, stream>>>(y2p, 10, 16, 32 * 1000, a2, c2);

  conv3_p<<<dim3(6, 32), 256, 0, stream>>>(y2p, w3t, y3);

  pool_bn<<<1, 320, 0, stream>>>(y3, gamma, beta, out);
}

// Round 11
// 1616.071 us; speedup vs baseline: 2.0033x; 1.8648x over previous
//
#include <hip/hip_runtime.h>
#include <hip/hip_bf16.h>

#define EPSV 1e-5f
constexpr int NB = 32;

typedef short bf16x8 __attribute__((ext_vector_type(8)));
typedef short short4v __attribute__((ext_vector_type(4)));
typedef float f32x4 __attribute__((ext_vector_type(4)));

__device__ inline float bf2f(short s) {
  return __uint_as_float(((unsigned)(unsigned short)s) << 16);
}
__device__ inline short f2bf(float f) {
  unsigned u = __float_as_uint(f);
  unsigned r = (u + 0x7FFFu + ((u >> 16) & 1u)) >> 16;
  return (short)r;
}

// ---------------- x stats (NCDHW, C=1) ----------------
__global__ __launch_bounds__(256) void reduce_partial_f32(
    const float* __restrict__ in, int spatial, float* __restrict__ part,
    int totb, int boff)
{
  const int b = blockIdx.x;
  const int nblk = gridDim.x;
  float s = 0.f, s2 = 0.f;
  for (int n = 0; n < NB; ++n) {
    const float* p = in + (size_t)n * spatial;
    for (int i = b * 256 + threadIdx.x; i < spatial; i += nblk * 256) {
      float v = p[i];
      s += v; s2 += v * v;
    }
  }
  __shared__ float sh[256], sh2[256];
  int tid = threadIdx.x;
  sh[tid] = s; sh2[tid] = s2;
  __syncthreads();
  for (int off = 128; off > 0; off >>= 1) {
    if (tid < off) { sh[tid] += sh[tid + off]; sh2[tid] += sh2[tid + off]; }
    __syncthreads();
  }
  if (tid == 0) {
    part[(size_t)(boff + b) * 2 + 0] = sh[0];
    part[(size_t)(boff + b) * 2 + 1] = sh2[0];
  }
}

// ---------------- channels-last (rowlen 64) per-channel stats --------------
__global__ __launch_bounds__(256) void reduce_cl(
    const short* __restrict__ y, long nrows,
    float* __restrict__ part, int totb, int boff)
{
  const int b = blockIdx.x, nblk = gridDim.x;
  const int c = threadIdx.x & 63, seg = threadIdx.x >> 6;
  float s = 0.f, s2 = 0.f;
  for (long r = (long)b * 4 + seg; r < nrows; r += (long)nblk * 4) {
    float v = bf2f(y[r * 64 + c]);
    s += v; s2 += v * v;
  }
  __shared__ float sh[4][64], sh2[4][64];
  sh[seg][c] = s; sh2[seg][c] = s2;
  __syncthreads();
  if (seg == 0) {
    float a = sh[0][c] + sh[1][c] + sh[2][c] + sh[3][c];
    float a2 = sh2[0][c] + sh2[1][c] + sh2[2][c] + sh2[3][c];
    part[((size_t)c * totb + boff + b) * 2 + 0] = a;
    part[((size_t)c * totb + boff + b) * 2 + 1] = a2;
  }
}

__global__ __launch_bounds__(64) void reduce_final(
    const float* __restrict__ part, int nblk, int C, float* __restrict__ sums)
{
  const int c = blockIdx.x;
  float s = 0.f, s2 = 0.f;
  for (int b = threadIdx.x; b < nblk; b += 64) {
    s  += part[((size_t)c * nblk + b) * 2 + 0];
    s2 += part[((size_t)c * nblk + b) * 2 + 1];
  }
  for (int off = 32; off > 0; off >>= 1) {
    s  += __shfl_down(s, off);
    s2 += __shfl_down(s2, off);
  }
  if (threadIdx.x == 0) { sums[c] = s; sums[C + c] = s2; }
}

// ---------------- stats -> per-channel affine ----------------
__global__ __launch_bounds__(64) void aff_k(
    const float* __restrict__ st, const float* __restrict__ bias,
    float cnt_inv, int creal, float* __restrict__ a, float* __restrict__ c)
{
  int t = threadIdx.x;
  float mean = st[t] * cnt_inv;
  float var  = st[64 + t] * cnt_inv - mean * mean;
  float inv  = rsqrtf(var + EPSV);
  bool ok = t < creal;
  a[t] = ok ? inv : 0.f;
  c[t] = ok ? (-mean * inv + bias[t]) : 0.f;
}

// ---------------- weight repack: w[CO][CIN][125] fp32 -> wt[125][COP][64] ---
__global__ __launch_bounds__(256) void repack_k(
    const float* __restrict__ w, short* __restrict__ wt,
    int CO, int CIN, int COP)
{
  long total = 125L * COP * 64;
  for (long idx = (long)blockIdx.x * 256 + threadIdx.x; idx < total;
       idx += (long)gridDim.x * 256) {
    int tap = (int)(idx / (COP * 64));
    int r   = (int)(idx % (COP * 64));
    int co = r >> 6, ci = r & 63;
    float v = (co < CO && ci < CIN) ? w[((size_t)co * CIN + ci) * 125 + tap] : 0.f;
    wt[idx] = f2bf(v);
  }
}

// ---------------- w0 repack: w0[52][125] -> w0t[64 co][128 k] ---------------
__global__ __launch_bounds__(256) void repack_w0(
    const float* __restrict__ w, short* __restrict__ wt)
{
  for (int idx = blockIdx.x * 256 + threadIdx.x; idx < 64 * 128;
       idx += gridDim.x * 256) {
    int co = idx >> 7, k = idx & 127;
    float v = (co < 52 && k < 125) ? w[co * 125 + k] : 0.f;
    wt[idx] = f2bf(v);
  }
}

// ---------------- conv0 MFMA: CIN=1, K=125 taps, BN(x) on stage -------------
// out channels-last [img][33^3][64] (co 52..63 exact zeros via zero weights)
__global__ __launch_bounds__(256) void conv0_mfma(
    const float* __restrict__ x, const short* __restrict__ w0t,
    const float* __restrict__ stats, short* __restrict__ out,
    int n_in0, int n_out0)
{
  constexpr int IN = 64, OUT = 33;
  constexpr float CNTI = 1.0f / ((float)NB * IN * IN * IN);
  __shared__ __align__(16) char slab[64 * 256];

  const int tid = threadIdx.x;
  const int wv = tid >> 6, ln = tid & 63;
  const int cs = ln >> 4;
  const int ntile0 = blockIdx.x * 64;
  const int od = blockIdx.y;
  const int img = blockIdx.z;

  const float mean = stats[0] * CNTI;
  const float inv  = rsqrtf(stats[1] * CNTI - mean * mean + EPSV);

  bf16x8 afr[4];
  {
    const short* wrow = w0t + (wv * 16 + (ln & 15)) * 128 + cs * 8;
    #pragma unroll
    for (int ks = 0; ks < 4; ++ks) afr[ks] = *(const bf16x8*)(wrow + ks * 32);
  }

  const float* xi = x + (size_t)(n_in0 + img) * (IN * IN * IN);
  const int id_base = 2 * od - 3;
  for (int u = tid; u < 1024; u += 256) {
    const int nl = u >> 4, s = u & 15;
    const int ng = ntile0 + nl;
    const int oh = ng / OUT, ow = ng - oh * OUT;
    const bool nok = ng < OUT * OUT;
    const int ih_base = 2 * oh - 3, iw_base = 2 * ow - 3;
    bf16x8 pk;
    #pragma unroll
    for (int e = 0; e < 8; ++e) {
      const int k = s * 8 + e;
      float f = 0.f;
      if (nok && k < 125) {
        const int kd = k / 25, r = k - kd * 25;
        const int kh = r / 5, kw = r - kh * 5;
        const int id = id_base + kd, ih = ih_base + kh, iw = iw_base + kw;
        if ((unsigned)id < (unsigned)IN && (unsigned)ih < (unsigned)IN &&
            (unsigned)iw < (unsigned)IN)
          f = (xi[((size_t)id * IN + ih) * IN + iw] - mean) * inv;
      }
      pk[e] = f2bf(f);
    }
    const int slot = (s & 8) | ((s & 7) ^ (nl & 7));
    *(bf16x8*)(slab + nl * 256 + slot * 16) = pk;
  }
  __syncthreads();

  const int nl = ln & 15;
  #pragma unroll
  for (int nt = 0; nt < 4; ++nt) {
    f32x4 acc = (f32x4){0.f, 0.f, 0.f, 0.f};
    const int nn = nt * 16 + nl;
    #pragma unroll
    for (int ks = 0; ks < 4; ++ks) {
      const int s = ks * 4 + cs;
      const int slot = (s & 8) | ((s & 7) ^ (nn & 7));
      bf16x8 b = *(const bf16x8*)(slab + nn * 256 + slot * 16);
      acc = __builtin_amdgcn_mfma_f32_16x16x32_bf16(afr[ks], b, acc, 0, 0, 0);
    }
    const int ng = ntile0 + nn;
    if (ng < OUT * OUT) {
      const int oh = ng / OUT, ow = ng - oh * OUT;
      short4v pk;
      #pragma unroll
      for (int r = 0; r < 4; ++r) pk[r] = f2bf(acc[r]);
      size_t base = ((((size_t)(n_out0 + img) * OUT + od) * OUT + oh) * OUT + ow) * 64;
      *(short4v*)(out + base + wv * 16 + cs * 4) = pk;
    }
  }
}

// ---------------- slab swizzle ----------------
__device__ inline int swz(int lin, int cs) {
  int row = lin >> 1;
  int slot = (((lin & 1) << 2) | cs) ^ (row & 7);
  return row * 128 + slot * 16;
}

// ---------------- main conv: 2m x 2n waves, BN+ReLU on stage ---------------
// 4 waves = 2 m-groups x 2 n-groups; wave owns 2 m-tiles x 2 n-tiles.
// Per kh: 10 A-frags (global L2), 10 B ds_reads, 20 MFMA (0.5 ds/MFMA).
template<int IN, int OUT, int OHG>
__global__ __launch_bounds__(256) void conv_2m2n(
    const short* __restrict__ yin, const short* __restrict__ wt,
    const float* __restrict__ affa, const float* __restrict__ affc,
    short* __restrict__ yout, int n_in0, int n_out0)
{
  constexpr int W = 2 * OUT + 3;
  constexpr int H = 2 * OHG + 3;
  constexpr int LIN = H * W;
  constexpr int ROWS = (LIN + 1) / 2;
  constexpr int LINM = LIN - 1 - 4 * W - 4;

  __shared__ __align__(16) char slab[ROWS * 128];
  __shared__ float s_a[64], s_c[64];

  const int tid = threadIdx.x;
  const int wv = tid >> 6, ln = tid & 63;
  const int nl = ln & 15, cs = ln >> 4;
  const int wm = wv >> 1, wn = wv & 1;
  const int oh0 = blockIdx.x * OHG;
  const int od  = blockIdx.y;
  const int nimg = blockIdx.z;

  if (tid < 64) { s_a[tid] = affa[tid]; s_c[tid] = affc[tid]; }

  int lb[2]; bool vld[2]; size_t obase[2];
  #pragma unroll
  for (int j = 0; j < 2; ++j) {
    int nt = 2 * wn + j;
    int n = nt * 16 + nl;
    int ohl = n / OUT, ow = n - ohl * OUT;
    vld[j] = n < OHG * OUT;
    int l = 2 * ohl * W + 2 * ow;
    lb[j] = (l > LINM) ? LINM : l;
    obase[j] = ((((size_t)(n_out0 + nimg) * OUT + od) * OUT + (oh0 + ohl)) * OUT + ow) * 64;
  }

  f32x4 acc[2][2];
  #pragma unroll
  for (int mi = 0; mi < 2; ++mi)
    #pragma unroll
    for (int j = 0; j < 2; ++j) acc[mi][j] = (f32x4){0.f, 0.f, 0.f, 0.f};

  const int id_base = 2 * od - 3;
  const int ih_base = 2 * oh0 - 3;

  for (int ch = 0; ch < 2; ++ch) {
    for (int kd = 0; kd < 5; ++kd) {
      __syncthreads();
      {  // ---- stage: relu(a*y + c), one (cin-half, kd) plane ----
        const int id = id_base + kd;
        const bool dok = (unsigned)id < (unsigned)IN;
        for (int u = tid; u < LIN * 4; u += 256) {
          int lin = u >> 2, cs2 = u & 3;
          int hl = lin / W, wl = lin - hl * W;
          int ih = ih_base + hl;
          int iw = wl - 3;
          bf16x8 pk;
          if (dok && (unsigned)ih < (unsigned)IN && (unsigned)iw < (unsigned)IN) {
            size_t base = ((((size_t)nimg * IN + id) * IN + ih) * IN + iw) * 64
                          + ch * 32 + cs2 * 8;
            bf16x8 ld = *(const bf16x8*)(yin + base);
            #pragma unroll
            for (int e = 0; e < 8; ++e) {
              int c = ch * 32 + cs2 * 8 + e;
              pk[e] = f2bf(fmaxf(s_a[c] * bf2f(ld[e]) + s_c[c], 0.f));
            }
          } else {
            #pragma unroll
            for (int e = 0; e < 8; ++e) pk[e] = 0;
          }
          *(bf16x8*)(slab + swz(lin, cs2)) = pk;
        }
      }
      __syncthreads();
      // ---- compute: per kh, 10 A-frags + 10 ds_reads -> 20 MFMA ----
      for (int kh = 0; kh < 5; ++kh) {
        const int tapb = (kd * 5 + kh) * 5;
        bf16x8 afr[2][5];
        #pragma unroll
        for (int mi = 0; mi < 2; ++mi)
          #pragma unroll
          for (int kw = 0; kw < 5; ++kw)
            afr[mi][kw] = *(const bf16x8*)(
                wt + ((size_t)(tapb + kw) * 64 + (2 * wm + mi) * 16 + nl) * 64
                + ch * 32 + cs * 8);
        #pragma unroll
        for (int kw = 0; kw < 5; ++kw) {
          bf16x8 b0 = *(const bf16x8*)(slab + swz(lb[0] + kh * W + kw, cs));
          bf16x8 b1 = *(const bf16x8*)(slab + swz(lb[1] + kh * W + kw, cs));
          #pragma unroll
          for (int mi = 0; mi < 2; ++mi) {
            acc[mi][0] = __builtin_amdgcn_mfma_f32_16x16x32_bf16(
                afr[mi][kw], b0, acc[mi][0], 0, 0, 0);
            acc[mi][1] = __builtin_amdgcn_mfma_f32_16x16x32_bf16(
                afr[mi][kw], b1, acc[mi][1], 0, 0, 0);
          }
        }
      }
    }
  }

  #pragma unroll
  for (int j = 0; j < 2; ++j) {
    if (!vld[j]) continue;
    #pragma unroll
    for (int mi = 0; mi < 2; ++mi) {
      short4v pk;
      #pragma unroll
      for (int r = 0; r < 4; ++r) pk[r] = f2bf(acc[mi][j][r]);
      *(short4v*)(yout + obase[j] + (2 * wm + mi) * 16 + cs * 4) = pk;
    }
  }
}

// ---------------- conv3: M-split, CO=16 (proven r5 path) -------------------
__global__ __launch_bounds__(256) void conv3_m(
    const short* __restrict__ yin, const short* __restrict__ wt,
    const float* __restrict__ affa, const float* __restrict__ affc,
    short* __restrict__ yout)
{
  constexpr int IN = 10, OUT = 6;
  constexpr int W = 15, H = 15, LIN = 225, ROWS = 113;
  constexpr int LINM = LIN - 1 - 4 * W - 4;
  __shared__ __align__(16) char slab[ROWS * 128];
  __shared__ float s_a[64], s_c[64];

  const int tid = threadIdx.x, wv = tid >> 6, ln = tid & 63;
  const int nl = ln & 15, cs = ln >> 4;
  const int od = blockIdx.x, nimg = blockIdx.y;

  if (tid < 64) { s_a[tid] = affa[tid]; s_c[tid] = affc[tid]; }

  const int nn = wv * 16 + nl;       // waves 0..2 active (36 outputs)
  const bool act = wv < 3;
  const bool vld = act && nn < 36;
  int ohl = nn / 6, ow = nn - ohl * 6;
  int lb = 2 * ohl * W + 2 * ow;
  if (lb > LINM) lb = LINM;
  const size_t obase = ((((size_t)nimg * 6 + od) * 6 + ohl) * 6 + ow) * 16;

  f32x4 acc = (f32x4){0.f, 0.f, 0.f, 0.f};
  const int id_base = 2 * od - 3;

  for (int ch = 0; ch < 2; ++ch) {
    for (int kd = 0; kd < 5; ++kd) {
      const int id = id_base + kd;
      const bool dok = (unsigned)id < (unsigned)IN;
      __syncthreads();
      for (int u = tid; u < 900; u += 256) {
        int lin = u >> 2, cs2 = u & 3;
        int hl = lin / 15, wl = lin - hl * 15;
        int ih = hl - 3, iw = wl - 3;
        bf16x8 pk;
        if (dok && (unsigned)ih < (unsigned)IN && (unsigned)iw < (unsigned)IN) {
          bf16x8 ld = *(const bf16x8*)(yin + ((((size_t)nimg * IN + id) * IN + ih) * IN + iw) * 64
                                       + ch * 32 + cs2 * 8);
          #pragma unroll
          for (int e = 0; e < 8; ++e) {
            int c = ch * 32 + cs2 * 8 + e;
            pk[e] = f2bf(fmaxf(s_a[c] * bf2f(ld[e]) + s_c[c], 0.f));
          }
        } else {
          #pragma unroll
          for (int e = 0; e < 8; ++e) pk[e] = 0;
        }
        *(bf16x8*)(slab + swz(lin, cs2)) = pk;
      }
      __syncthreads();
      if (act) {
        for (int kh = 0; kh < 5; ++kh) {
          const int tapb = (kd * 5 + kh) * 5;
          bf16x8 afr[5];
          #pragma unroll
          for (int kw = 0; kw < 5; ++kw)
            afr[kw] = *(const bf16x8*)(wt + ((size_t)(tapb + kw) * 16 + nl) * 64
                                       + ch * 32 + cs * 8);
          #pragma unroll
          for (int kw = 0; kw < 5; ++kw) {
            bf16x8 b = *(const bf16x8*)(slab + swz(lb + kh * W + kw, cs));
            acc = __builtin_amdgcn_mfma_f32_16x16x32_bf16(afr[kw], b, acc, 0, 0, 0);
          }
        }
      }
    }
  }
  if (vld) {
    short4v pk;
    #pragma unroll
    for (int r = 0; r < 4; ++r) pk[r] = f2bf(acc[r]);
    *(short4v*)(yout + obase + cs * 4) = pk;
  }
}

// ---------------- global avg pool + affine batch-dim BN (y3 CL-16) --------
__global__ __launch_bounds__(320) void pool_bn(
    const short* __restrict__ y3, const float* __restrict__ gamma,
    const float* __restrict__ beta, float* __restrict__ out)
{
  __shared__ float pool[320];
  const int t = threadIdx.x;
  const int n = t / 10, c = t % 10;
  const short* p = y3 + (size_t)n * 216 * 16 + c;
  float s = 0.f;
  for (int i = 0; i < 216; ++i) s += bf2f(p[i * 16]);
  const float pv = s * (1.0f / 216.0f);
  pool[t] = pv;
  __syncthreads();
  float m = 0.f, m2 = 0.f;
  for (int nn = 0; nn < 32; ++nn) {
    float v = pool[nn * 10 + c];
    m += v; m2 += v * v;
  }
  m *= (1.0f / 32.0f);
  m2 = m2 * (1.0f / 32.0f) - m * m;
  out[t] = (pv - m) * rsqrtf(m2 + EPSV) * gamma[c] + beta[c];
}

// ---------------- launcher ----------------
extern "C" void kernel_launch(void* const* d_in, const int* in_sizes, int n_in,
                              void* d_out, int out_size, void* d_ws, size_t ws_size,
                              hipStream_t stream)
{
  const float* x  = (const float*)d_in[0];
  const float* w0 = (const float*)d_in[1];
  const float* b0 = (const float*)d_in[2];
  const float* w1 = (const float*)d_in[3];
  const float* b1 = (const float*)d_in[4];
  const float* w2 = (const float*)d_in[5];
  const float* b2 = (const float*)d_in[6];
  const float* w3 = (const float*)d_in[7];
  const float* gamma = (const float*)d_in[8];
  const float* beta  = (const float*)d_in[9];
  float* out = (float*)d_out;

  char* base = (char*)d_ws;
  size_t off = 0;
  auto alloc = [&](size_t bytes) -> void* {
    void* p = base + off;
    off = (off + bytes + 255) & ~(size_t)255;
    return p;
  };
  short* y1  = (short*)alloc((size_t)32 * 5832 * 64 * 2);   // 23.9 MB
  short* y2  = (short*)alloc((size_t)32 * 1000 * 64 * 2);   //  4.1 MB
  short* y3  = (short*)alloc((size_t)32 * 216 * 16 * 2);    //  0.22 MB
  short* w1t = (short*)alloc((size_t)125 * 64 * 64 * 2);    //  1.0 MB
  short* w2t = (short*)alloc((size_t)125 * 64 * 64 * 2);
  short* w3t = (short*)alloc((size_t)125 * 16 * 64 * 2);
  short* w0t = (short*)alloc((size_t)64 * 128 * 2);
  float* st_in = (float*)alloc(1024);
  float* st0 = (float*)alloc(1024);
  float* st1 = (float*)alloc(1024);
  float* st2 = (float*)alloc(1024);
  float* a0 = (float*)alloc(256); float* c0 = (float*)alloc(256);
  float* a1 = (float*)alloc(256); float* c1 = (float*)alloc(256);
  float* a2 = (float*)alloc(256); float* c2 = (float*)alloc(256);
  float* part = (float*)alloc(64 * 1024 * 2 * 4);            // 512 KB
  short* y0 = (short*)(base + off);                          // remaining
  size_t rem = (ws_size > off + 256) ? (ws_size - off - 256) : 0;
  const size_t Y0_IMG = (size_t)35937 * 64;                  // CL64
  int CH;
  if      (rem >= Y0_IMG * 32 * 2) CH = 32;
  else if (rem >= Y0_IMG * 16 * 2) CH = 16;
  else if (rem >= Y0_IMG * 8 * 2)  CH = 8;
  else if (rem >= Y0_IMG * 4 * 2)  CH = 4;
  else if (rem >= Y0_IMG * 2 * 2)  CH = 2;
  else                             CH = 1;
  const int nch = 32 / CH;

  repack_k<<<512, 256, 0, stream>>>(w1, w1t, 52, 52, 64);
  repack_k<<<512, 256, 0, stream>>>(w2, w2t, 52, 52, 64);
  repack_k<<<256, 256, 0, stream>>>(w3, w3t, 10, 52, 16);
  repack_w0<<<32, 256, 0, stream>>>(w0, w0t);

  reduce_partial_f32<<<128, 256, 0, stream>>>(x, 64 * 64 * 64, part, 128, 0);
  reduce_final<<<1, 64, 0, stream>>>(part, 128, 1, st_in);

  const float cnt0 = 1.0f / ((float)NB * 35937.0f);
  const float cnt1 = 1.0f / ((float)NB * 5832.0f);
  const float cnt2 = 1.0f / ((float)NB * 1000.0f);

  if (CH == 32) {
    conv0_mfma<<<dim3(18, 33, 32), 256, 0, stream>>>(x, w0t, st_in, y0, 0, 0);
    reduce_cl<<<1024, 256, 0, stream>>>(y0, (long)32 * 35937, part, 1024, 0);
    reduce_final<<<64, 64, 0, stream>>>(part, 1024, 64, st0);
    aff_k<<<1, 64, 0, stream>>>(st0, b0, cnt0, 52, a0, c0);
    conv_2m2n<33, 18, 3><<<dim3(6, 18, 32), 256, 0, stream>>>(
        y0, w1t, a0, c0, y1, 0, 0);
  } else {
    for (int ck = 0; ck < nch; ++ck) {
      conv0_mfma<<<dim3(18, 33, CH), 256, 0, stream>>>(x, w0t, st_in, y0, ck * CH, 0);
      reduce_cl<<<32, 256, 0, stream>>>(y0, (long)CH * 35937, part, nch * 32, ck * 32);
    }
    reduce_final<<<64, 64, 0, stream>>>(part, nch * 32, 64, st0);
    aff_k<<<1, 64, 0, stream>>>(st0, b0, cnt0, 52, a0, c0);
    for (int ck = 0; ck < nch; ++ck) {
      conv0_mfma<<<dim3(18, 33, CH), 256, 0, stream>>>(x, w0t, st_in, y0, ck * CH, 0);
      conv_2m2n<33, 18, 3><<<dim3(6, 18, CH), 256, 0, stream>>>(
          y0, w1t, a0, c0, y1, 0, ck * CH);
    }
  }

  reduce_cl<<<256, 256, 0, stream>>>(y1, (long)32 * 5832, part, 256, 0);
  reduce_final<<<64, 64, 0, stream>>>(part, 256, 64, st1);
  aff_k<<<1, 64, 0, stream>>>(st1, b1, cnt1, 52, a1, c1);

  conv_2m2n<18, 10, 5><<<dim3(2, 10, 32), 256, 0, stream>>>(
      y1, w2t, a1, c1, y2, 0, 0);

  reduce_cl<<<32, 256, 0, stream>>>(y2, (long)32 * 1000, part, 32, 0);
  reduce_final<<<64, 64, 0, stream>>>(part, 32, 64, st2);
  aff_k<<<1, 64, 0, stream>>>(st2, b2, cnt2, 52, a2, c2);

  conv3_m<<<dim3(6, 32), 256, 0, stream>>>(y2, w3t, a2, c2, y3);

  pool_bn<<<1, 320, 0, stream>>>(y3, gamma, beta, out);
}